// Round 13
// baseline (348.995 us; speedup 1.0000x reference)
//
#include <hip/hip_runtime.h>
#include <hip/hip_bf16.h>

#define N     16384
#define FEAT  256
#define KSEL  8192
#define NBIN  32768            // bins = mono_key >> 49

typedef float f32x4 __attribute__((ext_vector_type(4)));

// Module-global intermediates. Invariants: g_hist is all-zero at entry to
// every call (.bss at load; k_scatter drains it back to exactly zero).
__device__ __align__(16) double   g_s[N];         // 128 KiB scores
__device__ __align__(16) unsigned long long g_key[N];   // 128 KiB mono keys
__device__ __align__(16) double   g_part[2048];   //  16 KiB sumsq partials
__device__ __align__(16) unsigned g_hist[NBIN];   // 128 KiB bin counts (0 at entry)
__device__ __align__(16) unsigned g_hist2[NBIN];  // 128 KiB suffix-exclusive
__device__ __align__(16) int      g_bucket[N];    //  64 KiB bin-grouped indices
__device__ __align__(16) int      g_sel[KSEL];    //  32 KiB
__device__ __align__(16) float    g_vals[KSEL];   //  32 KiB
__device__              double    g_norminv;

static __device__ __forceinline__ unsigned long long mono_key(double s) {
    unsigned long long u = (unsigned long long)__double_as_longlong(s);
    if (u & 0x8000000000000000ull) u = ~u;
    else                           u |= 0x8000000000000000ull;
    return u;
}

// K1: exact-f64 scores (one wave/row), mono keys, histogram, sumsq partials.
__global__ __launch_bounds__(512) void k_score(const float* __restrict__ x,
                                               const float* __restrict__ W) {
    __shared__ double s_p[8];
    int lane = threadIdx.x & 63;
    int wv   = threadIdx.x >> 6;
    int row  = blockIdx.x * 8 + wv;
    float4 xv = reinterpret_cast<const float4*>(x)[row * 64 + lane];
    float4 wvec = reinterpret_cast<const float4*>(W)[lane];
    double acc = (double)xv.x * (double)wvec.x + (double)xv.y * (double)wvec.y
               + (double)xv.z * (double)wvec.z + (double)xv.w * (double)wvec.w;
    #pragma unroll
    for (int m = 32; m >= 1; m >>= 1) acc += __shfl_xor(acc, m, 64);
    if (lane == 0) {
        unsigned long long k = mono_key(acc);
        g_s[row]   = acc;
        g_key[row] = k;
        atomicAdd(&g_hist[(unsigned)(k >> 49)], 1u);
        s_p[wv] = acc * acc;
    }
    __syncthreads();
    if (threadIdx.x == 0) {
        double p = 0.0;
        #pragma unroll
        for (int k = 0; k < 8; ++k) p += s_p[k];        // fixed order
        g_part[blockIdx.x] = p;
    }
}

// K2: single block: norminv reduce + suffix-exclusive scan of 32768 bins.
__global__ __launch_bounds__(1024) void k_scan() {
    __shared__ double red[1024];
    __shared__ unsigned Ts[1024];
    const int t = threadIdx.x;

    red[t] = g_part[t] + g_part[t + 1024];
    __syncthreads();
    for (int w = 512; w >= 1; w >>= 1) {
        if (t < w) red[t] += red[t + w];
        __syncthreads();
    }
    if (t == 0) g_norminv = 1.0 / sqrt(red[0]);

    // each thread owns bins [t*32, t*32+32)
    unsigned cnt[32]; unsigned S = 0;
    #pragma unroll
    for (int k = 0; k < 32; ++k) { cnt[k] = g_hist[t * 32 + k]; S += cnt[k]; }
    Ts[t] = S;
    __syncthreads();
    for (int off = 1; off < 1024; off <<= 1) {
        unsigned v = (t + off < 1024) ? Ts[t + off] : 0u;
        __syncthreads();
        Ts[t] += v;
        __syncthreads();
    }
    unsigned running = Ts[t] - S;                 // keys in bins >= (t+1)*32
    #pragma unroll
    for (int k = 31; k >= 0; --k) {               // high bin -> low bin
        g_hist2[t * 32 + k] = running;
        running += cnt[k];
    }
}

// K3: scatter indices into bin-grouped buckets; drains g_hist back to 0.
__global__ __launch_bounds__(256) void k_scatter() {
    int i = blockIdx.x * 256 + threadIdx.x;
    unsigned bin = (unsigned)(g_key[i] >> 49);
    int old = atomicSub((int*)&g_hist[bin], 1);   // old in [1..count]
    g_bucket[g_hist2[bin] + (unsigned)(old - 1)] = i;
}

// K4: exact rank = hist2[bin] + within-bin compares; fill sel/vals/idx.
__global__ __launch_bounds__(256) void k_ranksel(float* __restrict__ out_idx) {
    int i = blockIdx.x * 256 + threadIdx.x;
    unsigned long long ki = g_key[i];
    unsigned bin = (unsigned)(ki >> 49);
    unsigned base = g_hist2[bin];
    unsigned cntb = (bin == 0 ? (unsigned)N : g_hist2[bin - 1]) - base;
    unsigned c = 0;
    for (unsigned m = 0; m < cntb; ++m) {
        int j = g_bucket[base + m];
        unsigned long long kj = g_key[j];
        c += (unsigned)((kj > ki) | ((kj == ki) & (j < i)));
    }
    unsigned r = base + c;                        // descending rank, bijective
    if (r < (unsigned)KSEL) {
        g_sel[r]   = i;
        g_vals[r]  = tanhf((float)(g_s[i] * g_norminv));
        out_idx[r] = (float)i;
    }
}

// K5: gather (R7 structure; T14 split: all 8 segment loads issued before
// any LDS pack/write). 512 thr, 32 KiB bf16 row -> 4 blocks/CU.
__global__ __launch_bounds__(512) void k_gather(const float* __restrict__ x,
                                                const float* __restrict__ A,
                                                f32x4* __restrict__ outx,
                                                f32x4* __restrict__ outA) {
    __shared__ unsigned short rowb[N];            // 32 KiB bf16 row
    const int tid = threadIdx.x;
    int r = blockIdx.x;
    int srcr = g_sel[r] & (N - 1);

    const f32x4* src = reinterpret_cast<const f32x4*>(A + (size_t)srcr * N);
    f32x4 a[8];
    #pragma unroll
    for (int it = 0; it < 8; ++it)                // 8 x 16B in flight per lane
        a[it] = __builtin_nontemporal_load(src + it * 512 + tid);

    if (tid < 64) {                               // new_x while loads fly
        float v = g_vals[r];
        f32x4 xv = reinterpret_cast<const f32x4*>(x + (size_t)srcr * FEAT)[tid];
        outx[(size_t)r * (FEAT / 4) + tid] = xv * v;
    }

    uint2* rb = reinterpret_cast<uint2*>(rowb);
    #pragma unroll
    for (int it = 0; it < 8; ++it) {
        uint2 p;
        p.x = (__float_as_uint(a[it].y) & 0xFFFF0000u) | (__float_as_uint(a[it].x) >> 16);
        p.y = (__float_as_uint(a[it].w) & 0xFFFF0000u) | (__float_as_uint(a[it].z) >> 16);
        rb[it * 512 + tid] = p;
    }
    __syncthreads();

    const int4* sel4 = reinterpret_cast<const int4*>(g_sel);
    #pragma unroll
    for (int it = 0; it < (KSEL / 4) / 512; ++it) {
        int c4 = it * 512 + tid;
        int4 cc = sel4[c4];
        f32x4 o;
        o.x = __uint_as_float((unsigned)rowb[cc.x & (N - 1)] << 16);
        o.y = __uint_as_float((unsigned)rowb[cc.y & (N - 1)] << 16);
        o.z = __uint_as_float((unsigned)rowb[cc.z & (N - 1)] << 16);
        o.w = __uint_as_float((unsigned)rowb[cc.w & (N - 1)] << 16);
        __builtin_nontemporal_store(o, outA + (size_t)r * (KSEL / 4) + c4);
    }
}

extern "C" void kernel_launch(void* const* d_in, const int* in_sizes, int n_in,
                              void* d_out, int out_size, void* d_ws, size_t ws_size,
                              hipStream_t stream) {
    const float* x = nullptr; const float* A = nullptr; const float* W = nullptr;
    for (int i = 0; i < n_in; ++i) {
        if      (in_sizes[i] == N * FEAT) x = (const float*)d_in[i];
        else if (in_sizes[i] == N * N)    A = (const float*)d_in[i];
        else if (in_sizes[i] == FEAT)     W = (const float*)d_in[i];
    }
    if (!x || !A || !W) return;

    float* out = (float*)d_out;                         // f32 output buffer
    float* out_x   = out;                               // [8192,256]
    float* out_A   = out + (size_t)KSEL * FEAT;         // [8192,8192]
    float* out_idx = out + (size_t)out_size - KSEL;     // [8192]

    hipLaunchKernelGGL(k_score,   dim3(N / 8),  dim3(512),  0, stream, x, W);
    hipLaunchKernelGGL(k_scan,    dim3(1),      dim3(1024), 0, stream);
    hipLaunchKernelGGL(k_scatter, dim3(N / 256), dim3(256), 0, stream);
    hipLaunchKernelGGL(k_ranksel, dim3(N / 256), dim3(256), 0, stream, out_idx);
    hipLaunchKernelGGL(k_gather,  dim3(KSEL),   dim3(512),  0, stream,
                       x, A, (f32x4*)out_x, (f32x4*)out_A);
}

// Round 14
// 190.291 us; speedup vs baseline: 1.8340x; 1.8340x over previous
//
#include <hip/hip_runtime.h>
#include <hip/hip_bf16.h>

#define N     16384
#define FEAT  256
#define KSEL  8192

typedef float f32x4 __attribute__((ext_vector_type(4)));

// Module-global intermediates (fully re-written every call; g_cnt re-zeroed
// by k_score, so the packed-atomic accumulation is replay-deterministic).
__device__ __align__(16) double g_s[N];        // 128 KiB scores
__device__ __align__(16) double g_part[2048];  //  16 KiB block sumsq partials
__device__ __align__(16) int    g_cnt[N];      //  64 KiB packed {cnt | contrib<<20}
__device__ __align__(16) int    g_sel[KSEL];   //  32 KiB
__device__ __align__(16) float  g_vals[KSEL];  //  32 KiB

// K1: exact-f64 scores (one wave per row), block sumsq partial, cnt zero.
__global__ __launch_bounds__(512) void k_score(const float* __restrict__ x,
                                               const float* __restrict__ W) {
    __shared__ double s_p[8];
    int lane = threadIdx.x & 63;
    int wv   = threadIdx.x >> 6;
    int row  = blockIdx.x * 8 + wv;
    float4 xv = reinterpret_cast<const float4*>(x)[row * 64 + lane];
    float4 wvec = reinterpret_cast<const float4*>(W)[lane];
    double acc = (double)xv.x * (double)wvec.x + (double)xv.y * (double)wvec.y
               + (double)xv.z * (double)wvec.z + (double)xv.w * (double)wvec.w;
    #pragma unroll
    for (int m = 32; m >= 1; m >>= 1) acc += __shfl_xor(acc, m, 64);
    if (lane == 0) { g_s[row] = acc; g_cnt[row] = 0; s_p[wv] = acc * acc; }
    __syncthreads();
    if (threadIdx.x == 0) {
        double p = 0.0;
        #pragma unroll
        for (int k = 0; k < 8; ++k) p += s_p[k];        // fixed order
        g_part[blockIdx.x] = p;
    }
}

// K2: rank (f64 compares, ties -> lower index) + fused norm + fused select.
// 1024 blocks x 256: block b -> i-group (b&63), j-chunk (b>>6).
// Wave 0 reduces g_part -> s_norm (hidden under LDS staging). The 16th
// chunk-contributor for each i finalizes sel/vals/idx — exactly-once, and
// the finalized values are independent of contributor arrival order.
__global__ __launch_bounds__(256) void k_ranksel(float* __restrict__ out_idx) {
    __shared__ double lk[1024];
    __shared__ double s_norm;
    const int tid = threadIdx.x;
    const int ig = blockIdx.x & 63, jc = blockIdx.x >> 6;
    for (int t = tid; t < 1024; t += 256) lk[t] = g_s[jc * 1024 + t];
    if (tid < 64) {
        double acc = 0.0;
        #pragma unroll
        for (int k = 0; k < 32; ++k) acc += g_part[k * 64 + tid];  // fixed tree
        #pragma unroll
        for (int m = 32; m >= 1; m >>= 1) acc += __shfl_xor(acc, m, 64);
        if (tid == 0) s_norm = 1.0 / sqrt(acc);
    }
    __syncthreads();
    int i = ig * 256 + tid;
    double si = g_s[i];
    int c = 0;
    #pragma unroll 8
    for (int jj = 0; jj < 1024; ++jj) {
        double sj = lk[jj];
        c += (int)((sj > si) | ((sj == si) & ((jc * 1024 + jj) < i)));
    }
    int old = atomicAdd(&g_cnt[i], c + (1 << 20));
    if ((old >> 20) == 15) {                    // this block is the 16th: finalize
        int r = (old & 0xFFFFF) + c;
        if ((unsigned)r < (unsigned)KSEL) {
            g_sel[r]   = i;
            g_vals[r]  = tanhf((float)(si * s_norm));
            out_idx[r] = (float)i;
        }
    }
}

// K3 (gather) — round-7 structure VERBATIM (best measured: 191.9 us).
//   wave 0:      new_x[r,:] = x[sel[r],:] * vals[r]
//   all threads: stage A[sel[r],:] as bf16 in LDS (32 KiB -> 4 blocks/CU),
//                then new_A[r,c] = row[sel[c]] (bf16->f32, err<=0.004)
__global__ __launch_bounds__(512) void k_gather(const float* __restrict__ x,
                                                const float* __restrict__ A,
                                                f32x4* __restrict__ outx,
                                                f32x4* __restrict__ outA) {
    __shared__ unsigned short rowb[N];          // 32 KiB bf16 row
    int r = blockIdx.x;
    int srcr = g_sel[r] & (N - 1);              // always in-bounds

    if (threadIdx.x < 64) {                     // new_x: one wave, 64 x float4
        float v = g_vals[r];
        f32x4 xv = reinterpret_cast<const f32x4*>(x + (size_t)srcr * FEAT)[threadIdx.x];
        outx[(size_t)r * (FEAT / 4) + threadIdx.x] = xv * v;
    }

    const f32x4* src = reinterpret_cast<const f32x4*>(A + (size_t)srcr * N);
    uint2* rb = reinterpret_cast<uint2*>(rowb);
    #pragma unroll
    for (int it = 0; it < (N / 4) / 512; ++it) {
        int t = it * 512 + threadIdx.x;
        f32x4 a = __builtin_nontemporal_load(src + t);
        uint2 p;
        p.x = (__float_as_uint(a.y) & 0xFFFF0000u) | (__float_as_uint(a.x) >> 16);
        p.y = (__float_as_uint(a.w) & 0xFFFF0000u) | (__float_as_uint(a.z) >> 16);
        rb[t] = p;                              // rowb[4t..4t+3] = bf16(a.xyzw)
    }
    __syncthreads();

    const int4* sel4 = reinterpret_cast<const int4*>(g_sel);
    #pragma unroll
    for (int it = 0; it < (KSEL / 4) / 512; ++it) {
        int c4 = it * 512 + threadIdx.x;
        int4 cc = sel4[c4];
        f32x4 o;
        o.x = __uint_as_float((unsigned)rowb[cc.x & (N - 1)] << 16);
        o.y = __uint_as_float((unsigned)rowb[cc.y & (N - 1)] << 16);
        o.z = __uint_as_float((unsigned)rowb[cc.z & (N - 1)] << 16);
        o.w = __uint_as_float((unsigned)rowb[cc.w & (N - 1)] << 16);
        __builtin_nontemporal_store(o, outA + (size_t)r * (KSEL / 4) + c4);
    }
}

extern "C" void kernel_launch(void* const* d_in, const int* in_sizes, int n_in,
                              void* d_out, int out_size, void* d_ws, size_t ws_size,
                              hipStream_t stream) {
    // Select input pointers BY SIZE — robust to any input ordering.
    const float* x = nullptr; const float* A = nullptr; const float* W = nullptr;
    for (int i = 0; i < n_in; ++i) {
        if      (in_sizes[i] == N * FEAT) x = (const float*)d_in[i];
        else if (in_sizes[i] == N * N)    A = (const float*)d_in[i];
        else if (in_sizes[i] == FEAT)     W = (const float*)d_in[i];
    }
    if (!x || !A || !W) return;

    float* out = (float*)d_out;                         // f32 output buffer
    float* out_x   = out;                               // [8192,256]
    float* out_A   = out + (size_t)KSEL * FEAT;         // [8192,8192]
    float* out_idx = out + (size_t)out_size - KSEL;     // [8192]

    hipLaunchKernelGGL(k_score,   dim3(N / 8), dim3(512), 0, stream, x, W);
    hipLaunchKernelGGL(k_ranksel, dim3(1024),  dim3(256), 0, stream, out_idx);
    hipLaunchKernelGGL(k_gather,  dim3(KSEL),  dim3(512), 0, stream,
                       x, A, (f32x4*)out_x, (f32x4*)out_A);
}